// Round 15
// baseline (133.645 us; speedup 1.0000x reference)
//
#include <hip/hip_runtime.h>

// Range-aware attention, bf16 MFMA pipeline.
// B=2, S=2048, D=1024, H=16, dk=64. EPS=0.1.
// R15 = R13 verbatim (best verified state, 132.7 us). R14's 32-rows/wave merge
// failed (3rd phantom in that direction) AND was parallelism-capped at 8
// waves/CU (2048 waves max) vs R13's 16 waves/CU — direction abandoned.

typedef __bf16 bf16x8 __attribute__((ext_vector_type(8)));
typedef float f32x4 __attribute__((ext_vector_type(4)));

#define EPSG 0.1f
// q pre-scale: 1/sqrt(dk) * log2(e)  -> scores come out in log2 domain
#define QSCALE 0.180336880f

__device__ __forceinline__ unsigned short f2bf(float f) {
  unsigned int u = __float_as_uint(f);
  u += 0x7FFFu + ((u >> 16) & 1u);   // RNE
  return (unsigned short)(u >> 16);
}

__device__ __forceinline__ unsigned cvt_pk_bf16(float a, float b) {
  unsigned r;
  asm("v_cvt_pk_bf16_f32 %0, %1, %2" : "=v"(r) : "v"(a), "v"(b));
  return r;  // lo16 = bf16(a), hi16 = bf16(b)
}

__device__ __forceinline__ void gload_lds16(const void* g, void* l) {
  __builtin_amdgcn_global_load_lds(
      (const __attribute__((address_space(1))) void*)g,
      (__attribute__((address_space(3))) void*)l, 16, 0, 0);
}

// ---------------- fp32 -> bf16 cast (all three inputs, one launch) ----------
__global__ __launch_bounds__(256) void cvt_all(const float* __restrict__ x,
                                               const float* __restrict__ wq,
                                               const float* __restrict__ wo,
                                               unsigned short* __restrict__ xb,
                                               unsigned short* __restrict__ wqb,
                                               unsigned short* __restrict__ wob) {
  const int i = blockIdx.x * 256 + threadIdx.x;  // float4 index, 2M total
  const float* in;
  unsigned short* out;
  int j;
  if (i < 1048576) {            // x: 4M floats
    in = x; out = xb; j = i;
  } else if (i < 1835008) {     // qkv_w: 3M floats
    in = wq; out = wqb; j = i - 1048576;
  } else {                      // out_w: 1M floats
    in = wo; out = wob; j = i - 1835008;
  }
  float4 v = ((const float4*)in)[j];
  ushort4 o;
  o.x = f2bf(v.x); o.y = f2bf(v.y); o.z = f2bf(v.z); o.w = f2bf(v.w);
  ((ushort4*)out)[j] = o;
}

// ---------------- shared GEMM pieces ----------------
__device__ __forceinline__ void stage128x64(const unsigned short* __restrict__ g,
                                            long ldb, long row0, long k0b,
                                            unsigned short* lds, int w, int l) {
  const char* gp = (const char*)g + (row0 + (long)(w * 8 + (l >> 3))) * ldb + k0b +
                   (long)(((l & 7) ^ (l >> 3)) << 4);
  char* lp = (char*)lds + w * 1024;
#pragma unroll
  for (int i = 0; i < 4; ++i) {
    gload_lds16(gp + (long)i * 32 * ldb, lp + i * 4096);
  }
}

__device__ __forceinline__ bf16x8 frag_ld(const unsigned short* lds, int row, int cb) {
  return *(const bf16x8*)((const char*)lds + row * 128 + (cb ^ ((row & 7) << 4)));
}

// XCD-chunked bijective block swizzle (T1): nwg must be divisible by 8.
__device__ __forceinline__ int xcd_swz(int lin, int nwg) {
  return (lin & 7) * (nwg >> 3) + (lin >> 3);
}

// 128x128 output tile, K=1024, A and B^T both row-major with 2048-byte rows.
__device__ __forceinline__ void gemm_loop(const unsigned short* __restrict__ A,
                                          const unsigned short* __restrict__ Bm,
                                          long m0, long n0,
                                          unsigned short* aT, unsigned short* bT,
                                          int w, int l, f32x4 acc[4][4]) {
  const int wr = (w >> 1) * 64, wc = (w & 1) * 64;
  const int l15 = l & 15;
  for (int ks = 0; ks < 1024; ks += 64) {
    __syncthreads();
    stage128x64(A, 2048, m0, (long)ks * 2, aT, w, l);
    stage128x64(Bm, 2048, n0, (long)ks * 2, bT, w, l);
    __syncthreads();
#pragma unroll
    for (int kk = 0; kk < 2; ++kk) {
      const int cb = kk * 64 + (l >> 4) * 16;
      bf16x8 af[4], bfr[4];
#pragma unroll
      for (int t = 0; t < 4; ++t) af[t] = frag_ld(aT, wr + t * 16 + l15, cb);
#pragma unroll
      for (int t = 0; t < 4; ++t) bfr[t] = frag_ld(bT, wc + t * 16 + l15, cb);
#pragma unroll
      for (int mt = 0; mt < 4; ++mt)
#pragma unroll
        for (int nt = 0; nt < 4; ++nt)
          acc[mt][nt] = __builtin_amdgcn_mfma_f32_16x16x32_bf16(af[mt], bfr[nt],
                                                                acc[mt][nt], 0, 0, 0);
    }
  }
}

// ---------------- QKV projection + clamp + layout scatter ----------------
// q stored PRE-SCALED by QSCALE (1/8 * log2e).  q,k -> [B*H][S][64]; v -> [B*H][64][S].
__global__ __launch_bounds__(256) void qkv_gemm(
    const unsigned short* __restrict__ xb, const unsigned short* __restrict__ wb,
    const float* __restrict__ bias,
    const float* __restrict__ akmin, const float* __restrict__ akmax,
    const float* __restrict__ avmin, const float* __restrict__ avmax,
    unsigned short* __restrict__ qo, unsigned short* __restrict__ ko,
    unsigned short* __restrict__ vto) {
  __shared__ __align__(16) unsigned short aT[128 * 64];
  __shared__ __align__(16) unsigned short bT[128 * 64];
  const int tid = threadIdx.x, l = tid & 63, w = tid >> 6;
  const int swz = xcd_swz(blockIdx.y * 24 + blockIdx.x, 24 * 32);
  const int bx = swz % 24, by = swz / 24;
  const long m0 = (long)by * 128, n0 = (long)bx * 128;
  f32x4 acc[4][4] = {};
  gemm_loop(xb, wb, m0, n0, aT, bT, w, l, acc);

  const int wr = (w >> 1) * 64, wc = (w & 1) * 64;
  const int l15 = l & 15, lg = l >> 4;
  const int t = (int)(n0 >> 10);  // uniform per block
#pragma unroll
  for (int nt = 0; nt < 4; ++nt) {
    const int n = (int)n0 + wc + nt * 16 + l15;
    const float bv = bias[n];
    const int h = (n >> 6) & 15, d = n & 63;
#pragma unroll
    for (int mt = 0; mt < 4; ++mt) {
      const long s0 = m0 + wr + mt * 16 + lg * 4;
      const int b = (int)(s0 >> 11), s_lo = (int)(s0 & 2047);
      const int bh = b * 16 + h;
      if (t == 0) {
#pragma unroll
        for (int j = 0; j < 4; ++j) {
          float v = (acc[mt][nt][j] + bv) * QSCALE;
          qo[((long)bh * 2048 + s_lo + j) * 64 + d] = f2bf(v);
        }
      } else if (t == 1) {
        const int ai = bh * 64 + d;
        const float amn = akmin[ai], amx = akmax[ai];
#pragma unroll
        for (int j = 0; j < 4; ++j) {
          float v = acc[mt][nt][j] + bv;
          float lo = fmaxf(v - EPSG, amn);
          float hi = fminf(v + EPSG, amx);
          lo = fminf(lo, hi);
          v = fmaxf(lo, fminf(v, hi));
          ko[((long)bh * 2048 + s_lo + j) * 64 + d] = f2bf(v);
        }
      } else {
        const int ai = bh * 64 + d;
        const float amn = avmin[ai], amx = avmax[ai];
        ushort4 pk;
        unsigned short* pp = (unsigned short*)&pk;
#pragma unroll
        for (int j = 0; j < 4; ++j) {
          float v = acc[mt][nt][j] + bv;
          float lo = fmaxf(v - EPSG, amn);
          float hi = fminf(v + EPSG, amx);
          lo = fminf(lo, hi);
          v = fmaxf(lo, fminf(v, hi));
          pp[j] = f2bf(v);
        }
        *(ushort4*)(vto + ((long)bh * 64 + d) * 2048 + s_lo) = pk;
      }
    }
  }
}

// ---------------- flash attention ----------------
// Best verified config (R13): block = 8 waves sharing one K/V tile pair (48KB
// LDS), grid 512 -> 2 blocks/CU = 16 waves/CU (the measured latency-hiding
// knee; q-parallelism optimum at 16 rows/wave). Each wave: 16 q-rows; staging
// 2 gloads/wave. Swapped operands; log2-domain scores; defer-max.
__global__ __launch_bounds__(512) void attn_fwd(
    const unsigned short* __restrict__ q, const unsigned short* __restrict__ k,
    const unsigned short* __restrict__ vt, unsigned short* __restrict__ o) {
  __shared__ __align__(16) unsigned short kT[2][64 * 64];
  __shared__ __align__(16) unsigned short vT[2][64 * 64];
  __shared__ __align__(16) unsigned short p_lds[8 * 16 * 64];
  const int tid = threadIdx.x, l = tid & 63, w = tid >> 6;  // w in 0..7
  const int l15 = l & 15, lg = l >> 4;

  // XCD swizzle: 512 blocks; linear%8 = dispatch XCD; 4-bh chunk per XCD.
  const int linear = blockIdx.y * 16 + blockIdx.x;
  const int idx = linear >> 3;
  const int bh = (linear & 7) * 4 + (idx >> 4);
  const int qt = idx & 15;  // 128-row q tile

  const char* kbC = (const char*)(k + (long)bh * 2048 * 64);
  const char* vbC = (const char*)(vt + (long)bh * 64 * 2048);

  // Q fragments (pre-scaled); used as the B-operand of the swapped QK^T.
  const unsigned short* qbase = q + ((long)bh * 2048 + qt * 128 + w * 16) * 64;
  bf16x8 qf[2];
#pragma unroll
  for (int kk = 0; kk < 2; ++kk)
    qf[kk] = *(const bf16x8*)(qbase + (long)l15 * 64 + kk * 32 + lg * 8);

  float m_run = -1e30f, l_part = 0.f;
  f32x4 oacc[4] = {};  // oacc[dt][j] = O[q=l15][d = dt*16 + lg*4 + j]

  unsigned short* pw = p_lds + w * 1024;  // per-wave [16 q-rows][64 kv] bf16
  const int pswz = (l15 & 7) << 4;
  char* pwrow = (char*)pw + l15 * 128;
  const int srow = l >> 3;                    // 0..7
  const int schk = ((l & 7) ^ srow) << 4;     // pre-swizzled source chunk

// 8 waves each stage 8 rows of K and 8 rows of V (1 gload each).
#define STAGE_KV(kt_, buf_)                                                      \
  do {                                                                           \
    const char* sK = kbC + (long)((kt_)*64 + w * 8 + srow) * 128 + schk;         \
    gload_lds16(sK, (char*)kT[buf_] + w * 1024);                                 \
    const char* sV = vbC + (long)(w * 8 + srow) * 4096 + (long)(kt_)*128 + schk; \
    gload_lds16(sV, (char*)vT[buf_] + w * 1024);                                 \
  } while (0)

  STAGE_KV(0, 0);
  asm volatile("s_waitcnt vmcnt(0)" ::: "memory");
  __syncthreads();

  for (int kt = 0; kt < 32; ++kt) {
    const int cur = kt & 1;
    if (kt < 31) STAGE_KV(kt + 1, cur ^ 1);
    const unsigned short* kTc = kT[cur];
    const unsigned short* vTc = vT[cur];

    // S^T = K @ Q^T : sc[ct][j] = S[q=l15][kv = ct*16 + lg*4 + j]  (log2 domain)
    f32x4 sc[4] = {};
    __builtin_amdgcn_s_setprio(1);
#pragma unroll
    for (int kk = 0; kk < 2; ++kk) {
      const int cb = kk * 64 + lg * 16;
#pragma unroll
      for (int ct = 0; ct < 4; ++ct) {
        const int row = ct * 16 + l15;
        bf16x8 kf = *(const bf16x8*)((const char*)kTc + row * 128 +
                                     (cb ^ ((row & 7) << 4)));
        sc[ct] = __builtin_amdgcn_mfma_f32_16x16x32_bf16(kf, qf[kk], sc[ct], 0, 0, 0);
      }
    }
    __builtin_amdgcn_s_setprio(0);

    // per-lane tile max over the lane's 16 scores
    float pm = fmaxf(fmaxf(fmaxf(sc[0][0], sc[0][1]), fmaxf(sc[0][2], sc[0][3])),
                     fmaxf(fmaxf(sc[1][0], sc[1][1]), fmaxf(sc[1][2], sc[1][3])));
    pm = fmaxf(pm,
               fmaxf(fmaxf(fmaxf(sc[2][0], sc[2][1]), fmaxf(sc[2][2], sc[2][3])),
                     fmaxf(fmaxf(sc[3][0], sc[3][1]), fmaxf(sc[3][2], sc[3][3]))));
    if (!__all(pm <= m_run + 11.5f)) {
      // slow path: row max = reduce across the 4 lanes sharing l15
      float mx = pm;
      mx = fmaxf(mx, __shfl_xor(mx, 16, 64));
      mx = fmaxf(mx, __shfl_xor(mx, 32, 64));
      mx = fmaxf(mx, m_run);
      const float alpha = __builtin_amdgcn_exp2f(m_run - mx);
      m_run = mx;
      l_part *= alpha;
#pragma unroll
      for (int dt = 0; dt < 4; ++dt) oacc[dt] *= alpha;
    }
    // P = exp2(S - m); pack pairs; 4x ds_write_b64 into per-wave P slab
    float rs = 0.f;
#pragma unroll
    for (int ct = 0; ct < 4; ++ct) {
      const float p0 = __builtin_amdgcn_exp2f(sc[ct][0] - m_run);
      const float p1 = __builtin_amdgcn_exp2f(sc[ct][1] - m_run);
      const float p2 = __builtin_amdgcn_exp2f(sc[ct][2] - m_run);
      const float p3 = __builtin_amdgcn_exp2f(sc[ct][3] - m_run);
      rs += (p0 + p1) + (p2 + p3);
      uint2 pk;
      pk.x = cvt_pk_bf16(p0, p1);
      pk.y = cvt_pk_bf16(p2, p3);
      *(uint2*)(pwrow + ((ct * 32 + lg * 8) ^ pswz)) = pk;
    }
    l_part += rs;

    // O^T += V^T @ P^T : oacc[dt] = mfma(vf[dt], pf[kk])
    __builtin_amdgcn_s_setprio(1);
#pragma unroll
    for (int kk = 0; kk < 2; ++kk) {
      const int cb = kk * 64 + lg * 16;
      bf16x8 pf = *(const bf16x8*)(pwrow + (cb ^ pswz));
#pragma unroll
      for (int dt = 0; dt < 4; ++dt) {
        const int row = dt * 16 + l15;
        bf16x8 vf = *(const bf16x8*)((const char*)vTc + row * 128 +
                                     (cb ^ ((row & 7) << 4)));
        oacc[dt] = __builtin_amdgcn_mfma_f32_16x16x32_bf16(vf, pf, oacc[dt], 0, 0, 0);
      }
    }
    __builtin_amdgcn_s_setprio(0);
    asm volatile("s_waitcnt vmcnt(0)" ::: "memory");
    __syncthreads();
  }

  // final row-sum across the 4 lanes sharing l15
  float rs = l_part;
  rs += __shfl_xor(rs, 16, 64);
  rs += __shfl_xor(rs, 32, 64);
  const float inv = 1.f / rs;

  const int b = bh >> 4, h = bh & 15;
  const long s = (long)qt * 128 + w * 16 + l15;
  unsigned short* orow = o + ((long)b * 2048 + s) * 1024 + h * 64;
#pragma unroll
  for (int dt = 0; dt < 4; ++dt) {
    uint2 pk;
    pk.x = cvt_pk_bf16(oacc[dt][0] * inv, oacc[dt][1] * inv);
    pk.y = cvt_pk_bf16(oacc[dt][2] * inv, oacc[dt][3] * inv);
    *(uint2*)(orow + dt * 16 + lg * 4) = pk;
  }
#undef STAGE_KV
}

// ---------------- output projection ----------------
__global__ __launch_bounds__(256) void out_gemm(const unsigned short* __restrict__ ab,
                                                const unsigned short* __restrict__ wb,
                                                const float* __restrict__ bias,
                                                float* __restrict__ out) {
  __shared__ __align__(16) unsigned short aT[128 * 64];
  __shared__ __align__(16) unsigned short bT[128 * 64];
  const int tid = threadIdx.x, l = tid & 63, w = tid >> 6;
  const int swz = xcd_swz(blockIdx.y * 8 + blockIdx.x, 8 * 32);
  const int bx = swz % 8, by = swz / 8;
  const long m0 = (long)by * 128, n0 = (long)bx * 128;
  f32x4 acc[4][4] = {};
  gemm_loop(ab, wb, m0, n0, aT, bT, w, l, acc);

  const int wr = (w >> 1) * 64, wc = (w & 1) * 64;
  const int l15 = l & 15, lg = l >> 4;
#pragma unroll
  for (int nt = 0; nt < 4; ++nt) {
    const int n = (int)n0 + wc + nt * 16 + l15;
    const float bv = bias[n];
#pragma unroll
    for (int mt = 0; mt < 4; ++mt) {
#pragma unroll
      for (int j = 0; j < 4; ++j) {
        const long m = m0 + wr + mt * 16 + lg * 4 + j;
        out[m * 1024 + n] = acc[mt][nt][j] + bv;
      }
    }
  }
}

extern "C" void kernel_launch(void* const* d_in, const int* in_sizes, int n_in,
                              void* d_out, int out_size, void* d_ws, size_t ws_size,
                              hipStream_t stream) {
  const float* x = (const float*)d_in[0];
  const float* qkv_w = (const float*)d_in[1];
  const float* qkv_b = (const float*)d_in[2];
  const float* out_w = (const float*)d_in[3];
  const float* out_b = (const float*)d_in[4];
  const float* akmin = (const float*)d_in[5];
  const float* akmax = (const float*)d_in[6];
  const float* avmin = (const float*)d_in[7];
  const float* avmax = (const float*)d_in[8];

  char* ws = (char*)d_ws;
  const long MB = 1024 * 1024;
  unsigned short* xb  = (unsigned short*)(ws + 0 * MB);    // 8 MB  [4096][1024]
  unsigned short* wqb = (unsigned short*)(ws + 8 * MB);    // 6 MB  [3072][1024]
  unsigned short* wob = (unsigned short*)(ws + 14 * MB);   // 2 MB  [1024][1024]
  unsigned short* qb  = (unsigned short*)(ws + 16 * MB);   // 8 MB  [32][2048][64] (q*QSCALE)
  unsigned short* kb  = (unsigned short*)(ws + 24 * MB);   // 8 MB  [32][2048][64]
  unsigned short* vtb = (unsigned short*)(ws + 32 * MB);   // 8 MB  [32][64][2048]
  unsigned short* ob  = (unsigned short*)(ws + 40 * MB);   // 8 MB  [4096][1024]

  cvt_all<<<8192, 256, 0, stream>>>(x, qkv_w, out_w, xb, wqb, wob);
  qkv_gemm<<<dim3(24, 32), 256, 0, stream>>>(xb, wqb, qkv_b, akmin, akmax, avmin,
                                             avmax, qb, kb, vtb);
  attn_fwd<<<dim3(16, 32), 512, 0, stream>>>(qb, kb, vtb, ob);
  out_gemm<<<dim3(8, 32), 256, 0, stream>>>(ob, wob, out_b, (float*)d_out);
}

// Round 16
// 128.337 us; speedup vs baseline: 1.0414x; 1.0414x over previous
//
#include <hip/hip_runtime.h>

// Range-aware attention, bf16 MFMA pipeline.
// B=2, S=2048, D=1024, H=16, dk=64. EPS=0.1.
// R16 = R15 (verified 133.6us) + qkv_gemm retiled 128x128 -> 128x96
// (grid 768->1024 blocks = 3->4 blocks/CU = 12->16 waves/CU, the measured
// latency-hiding knee from R11-R13). attn/out_gemm/cvt frozen.

typedef __bf16 bf16x8 __attribute__((ext_vector_type(8)));
typedef float f32x4 __attribute__((ext_vector_type(4)));

#define EPSG 0.1f
// q pre-scale: 1/sqrt(dk) * log2(e)  -> scores come out in log2 domain
#define QSCALE 0.180336880f

__device__ __forceinline__ unsigned short f2bf(float f) {
  unsigned int u = __float_as_uint(f);
  u += 0x7FFFu + ((u >> 16) & 1u);   // RNE
  return (unsigned short)(u >> 16);
}

__device__ __forceinline__ unsigned cvt_pk_bf16(float a, float b) {
  unsigned r;
  asm("v_cvt_pk_bf16_f32 %0, %1, %2" : "=v"(r) : "v"(a), "v"(b));
  return r;  // lo16 = bf16(a), hi16 = bf16(b)
}

__device__ __forceinline__ void gload_lds16(const void* g, void* l) {
  __builtin_amdgcn_global_load_lds(
      (const __attribute__((address_space(1))) void*)g,
      (__attribute__((address_space(3))) void*)l, 16, 0, 0);
}

// ---------------- fp32 -> bf16 cast (all three inputs, one launch) ----------
__global__ __launch_bounds__(256) void cvt_all(const float* __restrict__ x,
                                               const float* __restrict__ wq,
                                               const float* __restrict__ wo,
                                               unsigned short* __restrict__ xb,
                                               unsigned short* __restrict__ wqb,
                                               unsigned short* __restrict__ wob) {
  const int i = blockIdx.x * 256 + threadIdx.x;  // float4 index, 2M total
  const float* in;
  unsigned short* out;
  int j;
  if (i < 1048576) {            // x: 4M floats
    in = x; out = xb; j = i;
  } else if (i < 1835008) {     // qkv_w: 3M floats
    in = wq; out = wqb; j = i - 1048576;
  } else {                      // out_w: 1M floats
    in = wo; out = wob; j = i - 1835008;
  }
  float4 v = ((const float4*)in)[j];
  ushort4 o;
  o.x = f2bf(v.x); o.y = f2bf(v.y); o.z = f2bf(v.z); o.w = f2bf(v.w);
  ((ushort4*)out)[j] = o;
}

// ---------------- shared GEMM pieces ----------------
__device__ __forceinline__ void stage128x64(const unsigned short* __restrict__ g,
                                            long ldb, long row0, long k0b,
                                            unsigned short* lds, int w, int l) {
  const char* gp = (const char*)g + (row0 + (long)(w * 8 + (l >> 3))) * ldb + k0b +
                   (long)(((l & 7) ^ (l >> 3)) << 4);
  char* lp = (char*)lds + w * 1024;
#pragma unroll
  for (int i = 0; i < 4; ++i) {
    gload_lds16(gp + (long)i * 32 * ldb, lp + i * 4096);
  }
}

// 96-row variant: 3 gload rounds of 32 rows.
__device__ __forceinline__ void stage96x64(const unsigned short* __restrict__ g,
                                           long ldb, long row0, long k0b,
                                           unsigned short* lds, int w, int l) {
  const char* gp = (const char*)g + (row0 + (long)(w * 8 + (l >> 3))) * ldb + k0b +
                   (long)(((l & 7) ^ (l >> 3)) << 4);
  char* lp = (char*)lds + w * 1024;
#pragma unroll
  for (int i = 0; i < 3; ++i) {
    gload_lds16(gp + (long)i * 32 * ldb, lp + i * 4096);
  }
}

__device__ __forceinline__ bf16x8 frag_ld(const unsigned short* lds, int row, int cb) {
  return *(const bf16x8*)((const char*)lds + row * 128 + (cb ^ ((row & 7) << 4)));
}

// XCD-chunked bijective block swizzle (T1): nwg must be divisible by 8.
__device__ __forceinline__ int xcd_swz(int lin, int nwg) {
  return (lin & 7) * (nwg >> 3) + (lin >> 3);
}

// 128x128 output tile, K=1024, A and B^T both row-major with 2048-byte rows.
__device__ __forceinline__ void gemm_loop(const unsigned short* __restrict__ A,
                                          const unsigned short* __restrict__ Bm,
                                          long m0, long n0,
                                          unsigned short* aT, unsigned short* bT,
                                          int w, int l, f32x4 acc[4][4]) {
  const int wr = (w >> 1) * 64, wc = (w & 1) * 64;
  const int l15 = l & 15;
  for (int ks = 0; ks < 1024; ks += 64) {
    __syncthreads();
    stage128x64(A, 2048, m0, (long)ks * 2, aT, w, l);
    stage128x64(Bm, 2048, n0, (long)ks * 2, bT, w, l);
    __syncthreads();
#pragma unroll
    for (int kk = 0; kk < 2; ++kk) {
      const int cb = kk * 64 + (l >> 4) * 16;
      bf16x8 af[4], bfr[4];
#pragma unroll
      for (int t = 0; t < 4; ++t) af[t] = frag_ld(aT, wr + t * 16 + l15, cb);
#pragma unroll
      for (int t = 0; t < 4; ++t) bfr[t] = frag_ld(bT, wc + t * 16 + l15, cb);
#pragma unroll
      for (int mt = 0; mt < 4; ++mt)
#pragma unroll
        for (int nt = 0; nt < 4; ++nt)
          acc[mt][nt] = __builtin_amdgcn_mfma_f32_16x16x32_bf16(af[mt], bfr[nt],
                                                                acc[mt][nt], 0, 0, 0);
    }
  }
}

// ---------------- QKV projection + clamp + layout scatter (128x96 tile) -----
// q stored PRE-SCALED by QSCALE (1/8 * log2e).  q,k -> [B*H][S][64]; v -> [B*H][64][S].
// Tile 128(M) x 96(N): grid 32x32 = 1024 blocks -> 4 blocks/CU = 16 waves/CU.
// Waves 2x2; wave owns 64(M) x 48(N): acc[4][3]. t-branch moved per-fragment
// (n>>10; uniform over a fragment's 16 lanes since boundaries are 16-aligned).
__global__ __launch_bounds__(256) void qkv_gemm(
    const unsigned short* __restrict__ xb, const unsigned short* __restrict__ wb,
    const float* __restrict__ bias,
    const float* __restrict__ akmin, const float* __restrict__ akmax,
    const float* __restrict__ avmin, const float* __restrict__ avmax,
    unsigned short* __restrict__ qo, unsigned short* __restrict__ ko,
    unsigned short* __restrict__ vto) {
  __shared__ __align__(16) unsigned short aT[128 * 64];
  __shared__ __align__(16) unsigned short bT[96 * 64];
  const int tid = threadIdx.x, l = tid & 63, w = tid >> 6;
  const int swz = xcd_swz(blockIdx.y * 32 + blockIdx.x, 32 * 32);
  const int bx = swz & 31, by = swz >> 5;
  const long m0 = (long)by * 128, n0 = (long)bx * 96;

  const int wr = (w >> 1) * 64, wc = (w & 1) * 48;
  const int l15 = l & 15, lg = l >> 4;
  f32x4 acc[4][3] = {};
  for (int ks = 0; ks < 1024; ks += 64) {
    __syncthreads();
    stage128x64(xb, 2048, m0, (long)ks * 2, aT, w, l);
    stage96x64(wb, 2048, n0, (long)ks * 2, bT, w, l);
    __syncthreads();
#pragma unroll
    for (int kk = 0; kk < 2; ++kk) {
      const int cb = kk * 64 + lg * 16;
      bf16x8 af[4], bfr[3];
#pragma unroll
      for (int t = 0; t < 4; ++t) af[t] = frag_ld(aT, wr + t * 16 + l15, cb);
#pragma unroll
      for (int t = 0; t < 3; ++t) bfr[t] = frag_ld(bT, wc + t * 16 + l15, cb);
#pragma unroll
      for (int mt = 0; mt < 4; ++mt)
#pragma unroll
        for (int nt = 0; nt < 3; ++nt)
          acc[mt][nt] = __builtin_amdgcn_mfma_f32_16x16x32_bf16(af[mt], bfr[nt],
                                                                acc[mt][nt], 0, 0, 0);
    }
  }

#pragma unroll
  for (int nt = 0; nt < 3; ++nt) {
    const int n = (int)n0 + wc + nt * 16 + l15;
    const float bv = bias[n];
    const int t = n >> 10;          // uniform per fragment (16-aligned bounds)
    const int h = (n >> 6) & 15, d = n & 63;
#pragma unroll
    for (int mt = 0; mt < 4; ++mt) {
      const long s0 = m0 + wr + mt * 16 + lg * 4;
      const int b = (int)(s0 >> 11), s_lo = (int)(s0 & 2047);
      const int bh = b * 16 + h;
      if (t == 0) {
#pragma unroll
        for (int j = 0; j < 4; ++j) {
          float v = (acc[mt][nt][j] + bv) * QSCALE;
          qo[((long)bh * 2048 + s_lo + j) * 64 + d] = f2bf(v);
        }
      } else if (t == 1) {
        const int ai = bh * 64 + d;
        const float amn = akmin[ai], amx = akmax[ai];
#pragma unroll
        for (int j = 0; j < 4; ++j) {
          float v = acc[mt][nt][j] + bv;
          float lo = fmaxf(v - EPSG, amn);
          float hi = fminf(v + EPSG, amx);
          lo = fminf(lo, hi);
          v = fmaxf(lo, fminf(v, hi));
          ko[((long)bh * 2048 + s_lo + j) * 64 + d] = f2bf(v);
        }
      } else {
        const int ai = bh * 64 + d;
        const float amn = avmin[ai], amx = avmax[ai];
        ushort4 pk;
        unsigned short* pp = (unsigned short*)&pk;
#pragma unroll
        for (int j = 0; j < 4; ++j) {
          float v = acc[mt][nt][j] + bv;
          float lo = fmaxf(v - EPSG, amn);
          float hi = fminf(v + EPSG, amx);
          lo = fminf(lo, hi);
          v = fmaxf(lo, fminf(v, hi));
          pp[j] = f2bf(v);
        }
        *(ushort4*)(vto + ((long)bh * 64 + d) * 2048 + s_lo) = pk;
      }
    }
  }
}

// ---------------- flash attention ----------------
// Best verified config (R13): block = 8 waves sharing one K/V tile pair (48KB
// LDS), grid 512 -> 2 blocks/CU = 16 waves/CU (the measured latency-hiding
// knee; q-parallelism optimum at 16 rows/wave). Each wave: 16 q-rows; staging
// 2 gloads/wave. Swapped operands; log2-domain scores; defer-max.
__global__ __launch_bounds__(512) void attn_fwd(
    const unsigned short* __restrict__ q, const unsigned short* __restrict__ k,
    const unsigned short* __restrict__ vt, unsigned short* __restrict__ o) {
  __shared__ __align__(16) unsigned short kT[2][64 * 64];
  __shared__ __align__(16) unsigned short vT[2][64 * 64];
  __shared__ __align__(16) unsigned short p_lds[8 * 16 * 64];
  const int tid = threadIdx.x, l = tid & 63, w = tid >> 6;  // w in 0..7
  const int l15 = l & 15, lg = l >> 4;

  // XCD swizzle: 512 blocks; linear%8 = dispatch XCD; 4-bh chunk per XCD.
  const int linear = blockIdx.y * 16 + blockIdx.x;
  const int idx = linear >> 3;
  const int bh = (linear & 7) * 4 + (idx >> 4);
  const int qt = idx & 15;  // 128-row q tile

  const char* kbC = (const char*)(k + (long)bh * 2048 * 64);
  const char* vbC = (const char*)(vt + (long)bh * 64 * 2048);

  // Q fragments (pre-scaled); used as the B-operand of the swapped QK^T.
  const unsigned short* qbase = q + ((long)bh * 2048 + qt * 128 + w * 16) * 64;
  bf16x8 qf[2];
#pragma unroll
  for (int kk = 0; kk < 2; ++kk)
    qf[kk] = *(const bf16x8*)(qbase + (long)l15 * 64 + kk * 32 + lg * 8);

  float m_run = -1e30f, l_part = 0.f;
  f32x4 oacc[4] = {};  // oacc[dt][j] = O[q=l15][d = dt*16 + lg*4 + j]

  unsigned short* pw = p_lds + w * 1024;  // per-wave [16 q-rows][64 kv] bf16
  const int pswz = (l15 & 7) << 4;
  char* pwrow = (char*)pw + l15 * 128;
  const int srow = l >> 3;                    // 0..7
  const int schk = ((l & 7) ^ srow) << 4;     // pre-swizzled source chunk

// 8 waves each stage 8 rows of K and 8 rows of V (1 gload each).
#define STAGE_KV(kt_, buf_)                                                      \
  do {                                                                           \
    const char* sK = kbC + (long)((kt_)*64 + w * 8 + srow) * 128 + schk;         \
    gload_lds16(sK, (char*)kT[buf_] + w * 1024);                                 \
    const char* sV = vbC + (long)(w * 8 + srow) * 4096 + (long)(kt_)*128 + schk; \
    gload_lds16(sV, (char*)vT[buf_] + w * 1024);                                 \
  } while (0)

  STAGE_KV(0, 0);
  asm volatile("s_waitcnt vmcnt(0)" ::: "memory");
  __syncthreads();

  for (int kt = 0; kt < 32; ++kt) {
    const int cur = kt & 1;
    if (kt < 31) STAGE_KV(kt + 1, cur ^ 1);
    const unsigned short* kTc = kT[cur];
    const unsigned short* vTc = vT[cur];

    // S^T = K @ Q^T : sc[ct][j] = S[q=l15][kv = ct*16 + lg*4 + j]  (log2 domain)
    f32x4 sc[4] = {};
    __builtin_amdgcn_s_setprio(1);
#pragma unroll
    for (int kk = 0; kk < 2; ++kk) {
      const int cb = kk * 64 + lg * 16;
#pragma unroll
      for (int ct = 0; ct < 4; ++ct) {
        const int row = ct * 16 + l15;
        bf16x8 kf = *(const bf16x8*)((const char*)kTc + row * 128 +
                                     (cb ^ ((row & 7) << 4)));
        sc[ct] = __builtin_amdgcn_mfma_f32_16x16x32_bf16(kf, qf[kk], sc[ct], 0, 0, 0);
      }
    }
    __builtin_amdgcn_s_setprio(0);

    // per-lane tile max over the lane's 16 scores
    float pm = fmaxf(fmaxf(fmaxf(sc[0][0], sc[0][1]), fmaxf(sc[0][2], sc[0][3])),
                     fmaxf(fmaxf(sc[1][0], sc[1][1]), fmaxf(sc[1][2], sc[1][3])));
    pm = fmaxf(pm,
               fmaxf(fmaxf(fmaxf(sc[2][0], sc[2][1]), fmaxf(sc[2][2], sc[2][3])),
                     fmaxf(fmaxf(sc[3][0], sc[3][1]), fmaxf(sc[3][2], sc[3][3]))));
    if (!__all(pm <= m_run + 11.5f)) {
      // slow path: row max = reduce across the 4 lanes sharing l15
      float mx = pm;
      mx = fmaxf(mx, __shfl_xor(mx, 16, 64));
      mx = fmaxf(mx, __shfl_xor(mx, 32, 64));
      mx = fmaxf(mx, m_run);
      const float alpha = __builtin_amdgcn_exp2f(m_run - mx);
      m_run = mx;
      l_part *= alpha;
#pragma unroll
      for (int dt = 0; dt < 4; ++dt) oacc[dt] *= alpha;
    }
    // P = exp2(S - m); pack pairs; 4x ds_write_b64 into per-wave P slab
    float rs = 0.f;
#pragma unroll
    for (int ct = 0; ct < 4; ++ct) {
      const float p0 = __builtin_amdgcn_exp2f(sc[ct][0] - m_run);
      const float p1 = __builtin_amdgcn_exp2f(sc[ct][1] - m_run);
      const float p2 = __builtin_amdgcn_exp2f(sc[ct][2] - m_run);
      const float p3 = __builtin_amdgcn_exp2f(sc[ct][3] - m_run);
      rs += (p0 + p1) + (p2 + p3);
      uint2 pk;
      pk.x = cvt_pk_bf16(p0, p1);
      pk.y = cvt_pk_bf16(p2, p3);
      *(uint2*)(pwrow + ((ct * 32 + lg * 8) ^ pswz)) = pk;
    }
    l_part += rs;

    // O^T += V^T @ P^T : oacc[dt] = mfma(vf[dt], pf[kk])
    __builtin_amdgcn_s_setprio(1);
#pragma unroll
    for (int kk = 0; kk < 2; ++kk) {
      const int cb = kk * 64 + lg * 16;
      bf16x8 pf = *(const bf16x8*)(pwrow + (cb ^ pswz));
#pragma unroll
      for (int dt = 0; dt < 4; ++dt) {
        const int row = dt * 16 + l15;
        bf16x8 vf = *(const bf16x8*)((const char*)vTc + row * 128 +
                                     (cb ^ ((row & 7) << 4)));
        oacc[dt] = __builtin_amdgcn_mfma_f32_16x16x32_bf16(vf, pf, oacc[dt], 0, 0, 0);
      }
    }
    __builtin_amdgcn_s_setprio(0);
    asm volatile("s_waitcnt vmcnt(0)" ::: "memory");
    __syncthreads();
  }

  // final row-sum across the 4 lanes sharing l15
  float rs = l_part;
  rs += __shfl_xor(rs, 16, 64);
  rs += __shfl_xor(rs, 32, 64);
  const float inv = 1.f / rs;

  const int b = bh >> 4, h = bh & 15;
  const long s = (long)qt * 128 + w * 16 + l15;
  unsigned short* orow = o + ((long)b * 2048 + s) * 1024 + h * 64;
#pragma unroll
  for (int dt = 0; dt < 4; ++dt) {
    uint2 pk;
    pk.x = cvt_pk_bf16(oacc[dt][0] * inv, oacc[dt][1] * inv);
    pk.y = cvt_pk_bf16(oacc[dt][2] * inv, oacc[dt][3] * inv);
    *(uint2*)(orow + dt * 16 + lg * 4) = pk;
  }
#undef STAGE_KV
}

// ---------------- output projection ----------------
__global__ __launch_bounds__(256) void out_gemm(const unsigned short* __restrict__ ab,
                                                const unsigned short* __restrict__ wb,
                                                const float* __restrict__ bias,
                                                float* __restrict__ out) {
  __shared__ __align__(16) unsigned short aT[128 * 64];
  __shared__ __align__(16) unsigned short bT[128 * 64];
  const int tid = threadIdx.x, l = tid & 63, w = tid >> 6;
  const int swz = xcd_swz(blockIdx.y * 8 + blockIdx.x, 8 * 32);
  const int bx = swz % 8, by = swz / 8;
  const long m0 = (long)by * 128, n0 = (long)bx * 128;
  f32x4 acc[4][4] = {};
  gemm_loop(ab, wb, m0, n0, aT, bT, w, l, acc);

  const int wr = (w >> 1) * 64, wc = (w & 1) * 64;
  const int l15 = l & 15, lg = l >> 4;
#pragma unroll
  for (int nt = 0; nt < 4; ++nt) {
    const int n = (int)n0 + wc + nt * 16 + l15;
    const float bv = bias[n];
#pragma unroll
    for (int mt = 0; mt < 4; ++mt) {
#pragma unroll
      for (int j = 0; j < 4; ++j) {
        const long m = m0 + wr + mt * 16 + lg * 4 + j;
        out[m * 1024 + n] = acc[mt][nt][j] + bv;
      }
    }
  }
}

extern "C" void kernel_launch(void* const* d_in, const int* in_sizes, int n_in,
                              void* d_out, int out_size, void* d_ws, size_t ws_size,
                              hipStream_t stream) {
  const float* x = (const float*)d_in[0];
  const float* qkv_w = (const float*)d_in[1];
  const float* qkv_b = (const float*)d_in[2];
  const float* out_w = (const float*)d_in[3];
  const float* out_b = (const float*)d_in[4];
  const float* akmin = (const float*)d_in[5];
  const float* akmax = (const float*)d_in[6];
  const float* avmin = (const float*)d_in[7];
  const float* avmax = (const float*)d_in[8];

  char* ws = (char*)d_ws;
  const long MB = 1024 * 1024;
  unsigned short* xb  = (unsigned short*)(ws + 0 * MB);    // 8 MB  [4096][1024]
  unsigned short* wqb = (unsigned short*)(ws + 8 * MB);    // 6 MB  [3072][1024]
  unsigned short* wob = (unsigned short*)(ws + 14 * MB);   // 2 MB  [1024][1024]
  unsigned short* qb  = (unsigned short*)(ws + 16 * MB);   // 8 MB  [32][2048][64] (q*QSCALE)
  unsigned short* kb  = (unsigned short*)(ws + 24 * MB);   // 8 MB  [32][2048][64]
  unsigned short* vtb = (unsigned short*)(ws + 32 * MB);   // 8 MB  [32][64][2048]
  unsigned short* ob  = (unsigned short*)(ws + 40 * MB);   // 8 MB  [4096][1024]

  cvt_all<<<8192, 256, 0, stream>>>(x, qkv_w, out_w, xb, wqb, wob);
  qkv_gemm<<<dim3(32, 32), 256, 0, stream>>>(xb, wqb, qkv_b, akmin, akmax, avmin,
                                             avmax, qb, kb, vtb);
  attn_fwd<<<dim3(16, 32), 512, 0, stream>>>(qb, kb, vtb, ob);
  out_gemm<<<dim3(8, 32), 256, 0, stream>>>(ob, wob, out_b, (float*)d_out);
}

// Round 17
// 121.779 us; speedup vs baseline: 1.0974x; 1.0539x over previous
//
#include <hip/hip_runtime.h>

// Range-aware attention, bf16 MFMA pipeline.
// B=2, S=2048, D=1024, H=16, dk=64. EPS=0.1.
// R17 = R16 (verified 128.3us) + out_gemm retiled 128x128 -> 64x64
// (grid 256->1024 blocks = 1->4 blocks/CU = 4->16 waves/CU, the measured
// latency-hiding knee). attn/qkv/cvt frozen.

typedef __bf16 bf16x8 __attribute__((ext_vector_type(8)));
typedef float f32x4 __attribute__((ext_vector_type(4)));

#define EPSG 0.1f
// q pre-scale: 1/sqrt(dk) * log2(e)  -> scores come out in log2 domain
#define QSCALE 0.180336880f

__device__ __forceinline__ unsigned short f2bf(float f) {
  unsigned int u = __float_as_uint(f);
  u += 0x7FFFu + ((u >> 16) & 1u);   // RNE
  return (unsigned short)(u >> 16);
}

__device__ __forceinline__ unsigned cvt_pk_bf16(float a, float b) {
  unsigned r;
  asm("v_cvt_pk_bf16_f32 %0, %1, %2" : "=v"(r) : "v"(a), "v"(b));
  return r;  // lo16 = bf16(a), hi16 = bf16(b)
}

__device__ __forceinline__ void gload_lds16(const void* g, void* l) {
  __builtin_amdgcn_global_load_lds(
      (const __attribute__((address_space(1))) void*)g,
      (__attribute__((address_space(3))) void*)l, 16, 0, 0);
}

// ---------------- fp32 -> bf16 cast (all three inputs, one launch) ----------
__global__ __launch_bounds__(256) void cvt_all(const float* __restrict__ x,
                                               const float* __restrict__ wq,
                                               const float* __restrict__ wo,
                                               unsigned short* __restrict__ xb,
                                               unsigned short* __restrict__ wqb,
                                               unsigned short* __restrict__ wob) {
  const int i = blockIdx.x * 256 + threadIdx.x;  // float4 index, 2M total
  const float* in;
  unsigned short* out;
  int j;
  if (i < 1048576) {            // x: 4M floats
    in = x; out = xb; j = i;
  } else if (i < 1835008) {     // qkv_w: 3M floats
    in = wq; out = wqb; j = i - 1048576;
  } else {                      // out_w: 1M floats
    in = wo; out = wob; j = i - 1835008;
  }
  float4 v = ((const float4*)in)[j];
  ushort4 o;
  o.x = f2bf(v.x); o.y = f2bf(v.y); o.z = f2bf(v.z); o.w = f2bf(v.w);
  ((ushort4*)out)[j] = o;
}

// ---------------- shared GEMM pieces ----------------
__device__ __forceinline__ void stage128x64(const unsigned short* __restrict__ g,
                                            long ldb, long row0, long k0b,
                                            unsigned short* lds, int w, int l) {
  const char* gp = (const char*)g + (row0 + (long)(w * 8 + (l >> 3))) * ldb + k0b +
                   (long)(((l & 7) ^ (l >> 3)) << 4);
  char* lp = (char*)lds + w * 1024;
#pragma unroll
  for (int i = 0; i < 4; ++i) {
    gload_lds16(gp + (long)i * 32 * ldb, lp + i * 4096);
  }
}

// 96-row variant: 3 gload rounds of 32 rows.
__device__ __forceinline__ void stage96x64(const unsigned short* __restrict__ g,
                                           long ldb, long row0, long k0b,
                                           unsigned short* lds, int w, int l) {
  const char* gp = (const char*)g + (row0 + (long)(w * 8 + (l >> 3))) * ldb + k0b +
                   (long)(((l & 7) ^ (l >> 3)) << 4);
  char* lp = (char*)lds + w * 1024;
#pragma unroll
  for (int i = 0; i < 3; ++i) {
    gload_lds16(gp + (long)i * 32 * ldb, lp + i * 4096);
  }
}

// 64-row variant: 2 gload rounds of 32 rows.
__device__ __forceinline__ void stage64x64(const unsigned short* __restrict__ g,
                                           long ldb, long row0, long k0b,
                                           unsigned short* lds, int w, int l) {
  const char* gp = (const char*)g + (row0 + (long)(w * 8 + (l >> 3))) * ldb + k0b +
                   (long)(((l & 7) ^ (l >> 3)) << 4);
  char* lp = (char*)lds + w * 1024;
#pragma unroll
  for (int i = 0; i < 2; ++i) {
    gload_lds16(gp + (long)i * 32 * ldb, lp + i * 4096);
  }
}

__device__ __forceinline__ bf16x8 frag_ld(const unsigned short* lds, int row, int cb) {
  return *(const bf16x8*)((const char*)lds + row * 128 + (cb ^ ((row & 7) << 4)));
}

// XCD-chunked bijective block swizzle (T1): nwg must be divisible by 8.
__device__ __forceinline__ int xcd_swz(int lin, int nwg) {
  return (lin & 7) * (nwg >> 3) + (lin >> 3);
}

// ---------------- QKV projection + clamp + layout scatter (128x96 tile) -----
// q stored PRE-SCALED by QSCALE (1/8 * log2e).  q,k -> [B*H][S][64]; v -> [B*H][64][S].
// Tile 128(M) x 96(N): grid 32x32 = 1024 blocks -> 4 blocks/CU = 16 waves/CU.
__global__ __launch_bounds__(256) void qkv_gemm(
    const unsigned short* __restrict__ xb, const unsigned short* __restrict__ wb,
    const float* __restrict__ bias,
    const float* __restrict__ akmin, const float* __restrict__ akmax,
    const float* __restrict__ avmin, const float* __restrict__ avmax,
    unsigned short* __restrict__ qo, unsigned short* __restrict__ ko,
    unsigned short* __restrict__ vto) {
  __shared__ __align__(16) unsigned short aT[128 * 64];
  __shared__ __align__(16) unsigned short bT[96 * 64];
  const int tid = threadIdx.x, l = tid & 63, w = tid >> 6;
  const int swz = xcd_swz(blockIdx.y * 32 + blockIdx.x, 32 * 32);
  const int bx = swz & 31, by = swz >> 5;
  const long m0 = (long)by * 128, n0 = (long)bx * 96;

  const int wr = (w >> 1) * 64, wc = (w & 1) * 48;
  const int l15 = l & 15, lg = l >> 4;
  f32x4 acc[4][3] = {};
  for (int ks = 0; ks < 1024; ks += 64) {
    __syncthreads();
    stage128x64(xb, 2048, m0, (long)ks * 2, aT, w, l);
    stage96x64(wb, 2048, n0, (long)ks * 2, bT, w, l);
    __syncthreads();
#pragma unroll
    for (int kk = 0; kk < 2; ++kk) {
      const int cb = kk * 64 + lg * 16;
      bf16x8 af[4], bfr[3];
#pragma unroll
      for (int t = 0; t < 4; ++t) af[t] = frag_ld(aT, wr + t * 16 + l15, cb);
#pragma unroll
      for (int t = 0; t < 3; ++t) bfr[t] = frag_ld(bT, wc + t * 16 + l15, cb);
#pragma unroll
      for (int mt = 0; mt < 4; ++mt)
#pragma unroll
        for (int nt = 0; nt < 3; ++nt)
          acc[mt][nt] = __builtin_amdgcn_mfma_f32_16x16x32_bf16(af[mt], bfr[nt],
                                                                acc[mt][nt], 0, 0, 0);
    }
  }

#pragma unroll
  for (int nt = 0; nt < 3; ++nt) {
    const int n = (int)n0 + wc + nt * 16 + l15;
    const float bv = bias[n];
    const int t = n >> 10;          // uniform per fragment (16-aligned bounds)
    const int h = (n >> 6) & 15, d = n & 63;
#pragma unroll
    for (int mt = 0; mt < 4; ++mt) {
      const long s0 = m0 + wr + mt * 16 + lg * 4;
      const int b = (int)(s0 >> 11), s_lo = (int)(s0 & 2047);
      const int bh = b * 16 + h;
      if (t == 0) {
#pragma unroll
        for (int j = 0; j < 4; ++j) {
          float v = (acc[mt][nt][j] + bv) * QSCALE;
          qo[((long)bh * 2048 + s_lo + j) * 64 + d] = f2bf(v);
        }
      } else if (t == 1) {
        const int ai = bh * 64 + d;
        const float amn = akmin[ai], amx = akmax[ai];
#pragma unroll
        for (int j = 0; j < 4; ++j) {
          float v = acc[mt][nt][j] + bv;
          float lo = fmaxf(v - EPSG, amn);
          float hi = fminf(v + EPSG, amx);
          lo = fminf(lo, hi);
          v = fmaxf(lo, fminf(v, hi));
          ko[((long)bh * 2048 + s_lo + j) * 64 + d] = f2bf(v);
        }
      } else {
        const int ai = bh * 64 + d;
        const float amn = avmin[ai], amx = avmax[ai];
        ushort4 pk;
        unsigned short* pp = (unsigned short*)&pk;
#pragma unroll
        for (int j = 0; j < 4; ++j) {
          float v = acc[mt][nt][j] + bv;
          float lo = fmaxf(v - EPSG, amn);
          float hi = fminf(v + EPSG, amx);
          lo = fminf(lo, hi);
          v = fmaxf(lo, fminf(v, hi));
          pp[j] = f2bf(v);
        }
        *(ushort4*)(vto + ((long)bh * 64 + d) * 2048 + s_lo) = pk;
      }
    }
  }
}

// ---------------- flash attention ----------------
// Best verified config (R13): block = 8 waves sharing one K/V tile pair (48KB
// LDS), grid 512 -> 2 blocks/CU = 16 waves/CU. 16 q-rows/wave; swapped
// operands; log2-domain scores; defer-max.
__global__ __launch_bounds__(512) void attn_fwd(
    const unsigned short* __restrict__ q, const unsigned short* __restrict__ k,
    const unsigned short* __restrict__ vt, unsigned short* __restrict__ o) {
  __shared__ __align__(16) unsigned short kT[2][64 * 64];
  __shared__ __align__(16) unsigned short vT[2][64 * 64];
  __shared__ __align__(16) unsigned short p_lds[8 * 16 * 64];
  const int tid = threadIdx.x, l = tid & 63, w = tid >> 6;  // w in 0..7
  const int l15 = l & 15, lg = l >> 4;

  // XCD swizzle: 512 blocks; linear%8 = dispatch XCD; 4-bh chunk per XCD.
  const int linear = blockIdx.y * 16 + blockIdx.x;
  const int idx = linear >> 3;
  const int bh = (linear & 7) * 4 + (idx >> 4);
  const int qt = idx & 15;  // 128-row q tile

  const char* kbC = (const char*)(k + (long)bh * 2048 * 64);
  const char* vbC = (const char*)(vt + (long)bh * 64 * 2048);

  // Q fragments (pre-scaled); used as the B-operand of the swapped QK^T.
  const unsigned short* qbase = q + ((long)bh * 2048 + qt * 128 + w * 16) * 64;
  bf16x8 qf[2];
#pragma unroll
  for (int kk = 0; kk < 2; ++kk)
    qf[kk] = *(const bf16x8*)(qbase + (long)l15 * 64 + kk * 32 + lg * 8);

  float m_run = -1e30f, l_part = 0.f;
  f32x4 oacc[4] = {};  // oacc[dt][j] = O[q=l15][d = dt*16 + lg*4 + j]

  unsigned short* pw = p_lds + w * 1024;  // per-wave [16 q-rows][64 kv] bf16
  const int pswz = (l15 & 7) << 4;
  char* pwrow = (char*)pw + l15 * 128;
  const int srow = l >> 3;                    // 0..7
  const int schk = ((l & 7) ^ srow) << 4;     // pre-swizzled source chunk

// 8 waves each stage 8 rows of K and 8 rows of V (1 gload each).
#define STAGE_KV(kt_, buf_)                                                      \
  do {                                                                           \
    const char* sK = kbC + (long)((kt_)*64 + w * 8 + srow) * 128 + schk;         \
    gload_lds16(sK, (char*)kT[buf_] + w * 1024);                                 \
    const char* sV = vbC + (long)(w * 8 + srow) * 4096 + (long)(kt_)*128 + schk; \
    gload_lds16(sV, (char*)vT[buf_] + w * 1024);                                 \
  } while (0)

  STAGE_KV(0, 0);
  asm volatile("s_waitcnt vmcnt(0)" ::: "memory");
  __syncthreads();

  for (int kt = 0; kt < 32; ++kt) {
    const int cur = kt & 1;
    if (kt < 31) STAGE_KV(kt + 1, cur ^ 1);
    const unsigned short* kTc = kT[cur];
    const unsigned short* vTc = vT[cur];

    // S^T = K @ Q^T : sc[ct][j] = S[q=l15][kv = ct*16 + lg*4 + j]  (log2 domain)
    f32x4 sc[4] = {};
    __builtin_amdgcn_s_setprio(1);
#pragma unroll
    for (int kk = 0; kk < 2; ++kk) {
      const int cb = kk * 64 + lg * 16;
#pragma unroll
      for (int ct = 0; ct < 4; ++ct) {
        const int row = ct * 16 + l15;
        bf16x8 kf = *(const bf16x8*)((const char*)kTc + row * 128 +
                                     (cb ^ ((row & 7) << 4)));
        sc[ct] = __builtin_amdgcn_mfma_f32_16x16x32_bf16(kf, qf[kk], sc[ct], 0, 0, 0);
      }
    }
    __builtin_amdgcn_s_setprio(0);

    // per-lane tile max over the lane's 16 scores
    float pm = fmaxf(fmaxf(fmaxf(sc[0][0], sc[0][1]), fmaxf(sc[0][2], sc[0][3])),
                     fmaxf(fmaxf(sc[1][0], sc[1][1]), fmaxf(sc[1][2], sc[1][3])));
    pm = fmaxf(pm,
               fmaxf(fmaxf(fmaxf(sc[2][0], sc[2][1]), fmaxf(sc[2][2], sc[2][3])),
                     fmaxf(fmaxf(sc[3][0], sc[3][1]), fmaxf(sc[3][2], sc[3][3]))));
    if (!__all(pm <= m_run + 11.5f)) {
      // slow path: row max = reduce across the 4 lanes sharing l15
      float mx = pm;
      mx = fmaxf(mx, __shfl_xor(mx, 16, 64));
      mx = fmaxf(mx, __shfl_xor(mx, 32, 64));
      mx = fmaxf(mx, m_run);
      const float alpha = __builtin_amdgcn_exp2f(m_run - mx);
      m_run = mx;
      l_part *= alpha;
#pragma unroll
      for (int dt = 0; dt < 4; ++dt) oacc[dt] *= alpha;
    }
    // P = exp2(S - m); pack pairs; 4x ds_write_b64 into per-wave P slab
    float rs = 0.f;
#pragma unroll
    for (int ct = 0; ct < 4; ++ct) {
      const float p0 = __builtin_amdgcn_exp2f(sc[ct][0] - m_run);
      const float p1 = __builtin_amdgcn_exp2f(sc[ct][1] - m_run);
      const float p2 = __builtin_amdgcn_exp2f(sc[ct][2] - m_run);
      const float p3 = __builtin_amdgcn_exp2f(sc[ct][3] - m_run);
      rs += (p0 + p1) + (p2 + p3);
      uint2 pk;
      pk.x = cvt_pk_bf16(p0, p1);
      pk.y = cvt_pk_bf16(p2, p3);
      *(uint2*)(pwrow + ((ct * 32 + lg * 8) ^ pswz)) = pk;
    }
    l_part += rs;

    // O^T += V^T @ P^T : oacc[dt] = mfma(vf[dt], pf[kk])
    __builtin_amdgcn_s_setprio(1);
#pragma unroll
    for (int kk = 0; kk < 2; ++kk) {
      const int cb = kk * 64 + lg * 16;
      bf16x8 pf = *(const bf16x8*)(pwrow + (cb ^ pswz));
#pragma unroll
      for (int dt = 0; dt < 4; ++dt) {
        const int row = dt * 16 + l15;
        bf16x8 vf = *(const bf16x8*)((const char*)vTc + row * 128 +
                                     (cb ^ ((row & 7) << 4)));
        oacc[dt] = __builtin_amdgcn_mfma_f32_16x16x32_bf16(vf, pf, oacc[dt], 0, 0, 0);
      }
    }
    __builtin_amdgcn_s_setprio(0);
    asm volatile("s_waitcnt vmcnt(0)" ::: "memory");
    __syncthreads();
  }

  // final row-sum across the 4 lanes sharing l15
  float rs = l_part;
  rs += __shfl_xor(rs, 16, 64);
  rs += __shfl_xor(rs, 32, 64);
  const float inv = 1.f / rs;

  const int b = bh >> 4, h = bh & 15;
  const long s = (long)qt * 128 + w * 16 + l15;
  unsigned short* orow = o + ((long)b * 2048 + s) * 1024 + h * 64;
#pragma unroll
  for (int dt = 0; dt < 4; ++dt) {
    uint2 pk;
    pk.x = cvt_pk_bf16(oacc[dt][0] * inv, oacc[dt][1] * inv);
    pk.y = cvt_pk_bf16(oacc[dt][2] * inv, oacc[dt][3] * inv);
    *(uint2*)(orow + dt * 16 + lg * 4) = pk;
  }
#undef STAGE_KV
}

// ---------------- output projection (64x64 tile) ----------------
// Grid 16x64 = 1024 blocks -> 4 blocks/CU = 16 waves/CU (occupancy knee).
// 4 waves (2x2); wave owns 32x32: acc[2][2]. LDS 16 KB.
__global__ __launch_bounds__(256) void out_gemm(const unsigned short* __restrict__ ab,
                                                const unsigned short* __restrict__ wb,
                                                const float* __restrict__ bias,
                                                float* __restrict__ out) {
  __shared__ __align__(16) unsigned short aT[64 * 64];
  __shared__ __align__(16) unsigned short bT[64 * 64];
  const int tid = threadIdx.x, l = tid & 63, w = tid >> 6;
  const int swz = xcd_swz(blockIdx.y * 16 + blockIdx.x, 16 * 64);
  const int bx = swz & 15, by = swz >> 4;
  const long m0 = (long)by * 64, n0 = (long)bx * 64;

  const int wr = (w >> 1) * 32, wc = (w & 1) * 32;
  const int l15 = l & 15, lg = l >> 4;
  f32x4 acc[2][2] = {};
  for (int ks = 0; ks < 1024; ks += 64) {
    __syncthreads();
    stage64x64(ab, 2048, m0, (long)ks * 2, aT, w, l);
    stage64x64(wb, 2048, n0, (long)ks * 2, bT, w, l);
    __syncthreads();
#pragma unroll
    for (int kk = 0; kk < 2; ++kk) {
      const int cb = kk * 64 + lg * 16;
      bf16x8 af[2], bfr[2];
#pragma unroll
      for (int t = 0; t < 2; ++t) af[t] = frag_ld(aT, wr + t * 16 + l15, cb);
#pragma unroll
      for (int t = 0; t < 2; ++t) bfr[t] = frag_ld(bT, wc + t * 16 + l15, cb);
#pragma unroll
      for (int mt = 0; mt < 2; ++mt)
#pragma unroll
        for (int nt = 0; nt < 2; ++nt)
          acc[mt][nt] = __builtin_amdgcn_mfma_f32_16x16x32_bf16(af[mt], bfr[nt],
                                                                acc[mt][nt], 0, 0, 0);
    }
  }

#pragma unroll
  for (int nt = 0; nt < 2; ++nt) {
    const int n = (int)n0 + wc + nt * 16 + l15;
    const float bv = bias[n];
#pragma unroll
    for (int mt = 0; mt < 2; ++mt) {
#pragma unroll
      for (int j = 0; j < 4; ++j) {
        const long m = m0 + wr + mt * 16 + lg * 4 + j;
        out[m * 1024 + n] = acc[mt][nt][j] + bv;
      }
    }
  }
}

extern "C" void kernel_launch(void* const* d_in, const int* in_sizes, int n_in,
                              void* d_out, int out_size, void* d_ws, size_t ws_size,
                              hipStream_t stream) {
  const float* x = (const float*)d_in[0];
  const float* qkv_w = (const float*)d_in[1];
  const float* qkv_b = (const float*)d_in[2];
  const float* out_w = (const float*)d_in[3];
  const float* out_b = (const float*)d_in[4];
  const float* akmin = (const float*)d_in[5];
  const float* akmax = (const float*)d_in[6];
  const float* avmin = (const float*)d_in[7];
  const float* avmax = (const float*)d_in[8];

  char* ws = (char*)d_ws;
  const long MB = 1024 * 1024;
  unsigned short* xb  = (unsigned short*)(ws + 0 * MB);    // 8 MB  [4096][1024]
  unsigned short* wqb = (unsigned short*)(ws + 8 * MB);    // 6 MB  [3072][1024]
  unsigned short* wob = (unsigned short*)(ws + 14 * MB);   // 2 MB  [1024][1024]
  unsigned short* qb  = (unsigned short*)(ws + 16 * MB);   // 8 MB  [32][2048][64] (q*QSCALE)
  unsigned short* kb  = (unsigned short*)(ws + 24 * MB);   // 8 MB  [32][2048][64]
  unsigned short* vtb = (unsigned short*)(ws + 32 * MB);   // 8 MB  [32][64][2048]
  unsigned short* ob  = (unsigned short*)(ws + 40 * MB);   // 8 MB  [4096][1024]

  cvt_all<<<8192, 256, 0, stream>>>(x, qkv_w, out_w, xb, wqb, wob);
  qkv_gemm<<<dim3(32, 32), 256, 0, stream>>>(xb, wqb, qkv_b, akmin, akmax, avmin,
                                             avmax, qb, kb, vtb);
  attn_fwd<<<dim3(16, 32), 512, 0, stream>>>(qb, kb, vtb, ob);
  out_gemm<<<dim3(16, 64), 256, 0, stream>>>(ob, wob, out_b, (float*)d_out);
}